// Round 13
// baseline (391.045 us; speedup 1.0000x reference)
//
#include <hip/hip_runtime.h>
#include <hip/hip_bf16.h>
#include <cstdint>
#include <cstddef>

#define ATTN_OFF (2u*2048u*2048u)   // adjacency comes first in d_out
#define SLOTS 48                    // compact top-k slots per row
#define DELTA 1e-3f                 // band half-margin (>> bf16-split score err)
#define MAXB 32                     // max boundary elems per row
#define PVR 4                       // rows per pv_wo_es block

typedef __attribute__((ext_vector_type(8))) short bf16x8;
typedef __attribute__((ext_vector_type(4))) float f32x4;

__device__ __forceinline__ unsigned short bf16_hi(float f) {
  __hip_bfloat16 h = __float2bfloat16(f);
  return *(unsigned short*)&h;
}
__device__ __forceinline__ float bf16_val(unsigned short u) {
  __hip_bfloat16 h = *(__hip_bfloat16*)&u;
  return __bfloat162float(h);
}

// ---------------------------------------------------------------------------
// Fused node-embedding + Q/K/V low-rank chain, f64 math throughout. (R6 ok)
// ---------------------------------------------------------------------------
__global__ __launch_bounds__(256) void fused_qkv_kernel(
    const float* __restrict__ x, const float* __restrict__ ne_u,
    const float* __restrict__ ne_v, const float* __restrict__ wq_u,
    const float* __restrict__ wq_v, const float* __restrict__ wk_u,
    const float* __restrict__ wk_v, const float* __restrict__ wv_u,
    const float* __restrict__ wv_v, double* __restrict__ qd,
    double* __restrict__ kd, unsigned short* __restrict__ qh,
    unsigned short* __restrict__ ql, unsigned short* __restrict__ kh,
    unsigned short* __restrict__ kl, float* __restrict__ v) {
  __shared__ double xm[4][64];
  __shared__ double hrow[4][256];
  __shared__ double mid2[4][64];

  int tid = threadIdx.x;
  int rr = tid >> 6;
  int j  = tid & 63;
  int row = blockIdx.x * 4 + rr;
  int b = row >> 11, m = row & 2047;
  const double INV = 0.17677669529663688110021109052621;  // 1/sqrt(32)

  const float* xr = x + (size_t)row * 256;
  {
    double a0 = 0, a1 = 0, a2 = 0, a3 = 0;
#pragma unroll 8
    for (int k4 = 0; k4 < 64; ++k4) {
      int kk = k4 * 4;
      a0 = fma((double)xr[kk + 0], (double)ne_u[(kk + 0) * 64 + j], a0);
      a1 = fma((double)xr[kk + 1], (double)ne_u[(kk + 1) * 64 + j], a1);
      a2 = fma((double)xr[kk + 2], (double)ne_u[(kk + 2) * 64 + j], a2);
      a3 = fma((double)xr[kk + 3], (double)ne_u[(kk + 3) * 64 + j], a3);
    }
    xm[rr][j] = (a0 + a1) + (a2 + a3);
  }
  __syncthreads();

#pragma unroll
  for (int cc = 0; cc < 4; ++cc) {
    int col = j + 64 * cc;
    double o0 = 0, o1 = 0, o2 = 0, o3 = 0;
#pragma unroll 4
    for (int r4 = 0; r4 < 16; ++r4) {
      int r = r4 * 4;
      o0 = fma(xm[rr][r + 0], (double)ne_v[(r + 0) * 256 + col], o0);
      o1 = fma(xm[rr][r + 1], (double)ne_v[(r + 1) * 256 + col], o1);
      o2 = fma(xm[rr][r + 2], (double)ne_v[(r + 2) * 256 + col], o2);
      o3 = fma(xm[rr][r + 3], (double)ne_v[(r + 3) * 256 + col], o3);
    }
    hrow[rr][col] = (o0 + o1) + (o2 + o3);
  }
  __syncthreads();

  for (int p = 0; p < 3; ++p) {
    const float* pu = (p == 0) ? wq_u : (p == 1) ? wk_u : wv_u;
    const float* pw = (p == 0) ? wq_v : (p == 1) ? wk_v : wv_v;

    double a0 = 0, a1 = 0, a2 = 0, a3 = 0;
#pragma unroll 8
    for (int k4 = 0; k4 < 64; ++k4) {
      int kk = k4 * 4;
      a0 = fma(hrow[rr][kk + 0], (double)pu[(kk + 0) * 64 + j], a0);
      a1 = fma(hrow[rr][kk + 1], (double)pu[(kk + 1) * 64 + j], a1);
      a2 = fma(hrow[rr][kk + 2], (double)pu[(kk + 2) * 64 + j], a2);
      a3 = fma(hrow[rr][kk + 3], (double)pu[(kk + 3) * 64 + j], a3);
    }
    mid2[rr][j] = (a0 + a1) + (a2 + a3);
    __syncthreads();

#pragma unroll
    for (int cc = 0; cc < 4; ++cc) {
      int col = j + 64 * cc;
      double o0 = 0, o1 = 0, o2 = 0, o3 = 0;
#pragma unroll 4
      for (int r4 = 0; r4 < 16; ++r4) {
        int r = r4 * 4;
        o0 = fma(mid2[rr][r + 0], (double)pw[(r + 0) * 256 + col], o0);
        o1 = fma(mid2[rr][r + 1], (double)pw[(r + 1) * 256 + col], o1);
        o2 = fma(mid2[rr][r + 2], (double)pw[(r + 2) * 256 + col], o2);
        o3 = fma(mid2[rr][r + 3], (double)pw[(r + 3) * 256 + col], o3);
      }
      double o = (o0 + o1) + (o2 + o3);
      if (p == 2) {
        v[(size_t)row * 256 + col] = (float)o;
      } else {
        int hh = col >> 5, d = col & 31;
        size_t haddr = (((size_t)(b * 8 + hh)) * 2048 + m) * 32 + d;
        if (p == 0) {
          qd[(size_t)row * 256 + col] = o;
          float f = (float)(o * INV);
          unsigned short hi = bf16_hi(f);
          float lof = f - bf16_val(hi);
          qh[haddr] = hi;
          ql[haddr] = bf16_hi(lof);
        } else {
          kd[(size_t)row * 256 + col] = o;
          float f = (float)o;
          unsigned short hi = bf16_hi(f);
          float lof = f - bf16_val(hi);
          kh[haddr] = hi;
          kl[haddr] = bf16_hi(lof);
        }
      }
    }
    __syncthreads();
  }
}

// ---------------------------------------------------------------------------
// Fused scores (MFMA bf16 hi/lo 3-term) + exact top-32 via bucket-band
// selection (tiered histogram with range prefilter) + f64 band refinement +
// softmax + coalesced dense write. Zero-fill uses REGULAR stores (L2-cached):
// vmcnt acks at L2 accept, so the pre-scatter barrier doesn't stall for the
// HBM-depth drain that non-temporal stores incur. 7 barriers common path.
// ---------------------------------------------------------------------------
__global__ __launch_bounds__(512, 4) void attn_kernel(
    const unsigned short* __restrict__ qh, const unsigned short* __restrict__ ql,
    const unsigned short* __restrict__ kh, const unsigned short* __restrict__ kl,
    const double* __restrict__ qd, const double* __restrict__ kd,
    float* __restrict__ attn, float* __restrict__ pval,
    unsigned short* __restrict__ pidx) {
  __shared__ unsigned hist[16][64];
  __shared__ float sval[16][SLOTS];            // raw scores, then exp values
  __shared__ unsigned short scol[16][SLOTS];
  __shared__ float rowmax_s[16][8];
  __shared__ float mx_s[16];
  __shared__ float eLo_s[16], eHi_s[16];
  __shared__ float zinv_s[16];
  __shared__ int   kB_s[16];
  __shared__ unsigned scnt[16];
  __shared__ unsigned chi_s[16];
  __shared__ unsigned bcnt[16];
  __shared__ unsigned pend;
  __shared__ unsigned short bidx[16][MAXB];
  __shared__ float bval[16][MAXB];
  __shared__ double bs64[16][MAXB];

  int tid = threadIdx.x;
  int bx  = blockIdx.x;
  int slab = bx >> 7;
  int rowtile = bx & 127;
  int b = slab >> 3, hh = slab & 7;
  int w = tid >> 6;
  int l = tid & 63;
  int g = l >> 4;
  int li = l & 15;
  int h32 = l >> 5;            // 0/1: which 32-lane half of the wave
  int c32 = l & 31;            // lane within half
  int rw = w * 2 + h32;        // row owned in wide phases
  const double INV64 = 0.17677669529663688110021109052621;

  // ---- MFMA scores: 16 tiles x 3 (hi/lo split) ----
  size_t qoff = (((size_t)slab * 2048 + rowtile * 16 + li) * 32) + g * 8;
  bf16x8 a_hi = *(const bf16x8*)(qh + qoff);
  bf16x8 a_lo = *(const bf16x8*)(ql + qoff);

  float s[16][4];
  size_t kbase = ((size_t)slab * 2048 + w * 256 + li) * 32 + g * 8;
#pragma unroll
  for (int tt = 0; tt < 16; ++tt) {
    bf16x8 b_hi = *(const bf16x8*)(kh + kbase + (size_t)tt * 512);
    bf16x8 b_lo = *(const bf16x8*)(kl + kbase + (size_t)tt * 512);
    f32x4 acc = {0.f, 0.f, 0.f, 0.f};
    acc = __builtin_amdgcn_mfma_f32_16x16x32_bf16(a_hi, b_hi, acc, 0, 0, 0);
    acc = __builtin_amdgcn_mfma_f32_16x16x32_bf16(a_hi, b_lo, acc, 0, 0, 0);
    acc = __builtin_amdgcn_mfma_f32_16x16x32_bf16(a_lo, b_hi, acc, 0, 0, 0);
#pragma unroll
    for (int reg = 0; reg < 4; ++reg) s[tt][reg] = acc[reg];
  }

  // ---- init + per-slice row max ----
  for (int i = tid; i < 16 * 64; i += 512) ((unsigned*)hist)[i] = 0u;
  if (tid < 16) {
    scnt[tid] = 0u; chi_s[tid] = 0u; bcnt[tid] = 0u;
    kB_s[tid] = -1;
  }
  if (tid == 0) pend = 16u;
  size_t prow0 = ((size_t)slab * 2048 + rowtile * 16);
  {
    float lmx[4];
#pragma unroll
    for (int reg = 0; reg < 4; ++reg) {
      float m = s[0][reg];
#pragma unroll
      for (int tt = 1; tt < 16; ++tt) m = fmaxf(m, s[tt][reg]);
      lmx[reg] = m;
    }
#pragma unroll
    for (int off = 1; off < 16; off <<= 1) {
#pragma unroll
      for (int reg = 0; reg < 4; ++reg)
        lmx[reg] = fmaxf(lmx[reg], __shfl_xor(lmx[reg], (unsigned)off, 16));
    }
    if (li == 0) {
#pragma unroll
      for (int reg = 0; reg < 4; ++reg) rowmax_s[4 * g + reg][w] = lmx[reg];
    }
  }
  __syncthreads();   // b1

  // ---- block row max ----
  if (tid < 16) {
    float m = rowmax_s[tid][0];
#pragma unroll
    for (int i = 1; i < 8; ++i) m = fmaxf(m, rowmax_s[tid][i]);
    mx_s[tid] = m;
  }
  __syncthreads();   // b2

  // ---- tiered histogram: locate kth bucket (tier 0 almost always) ----
#pragma unroll
  for (int tier = 0; tier < 3; ++tier) {
    if (pend != 0u) {      // block-uniform (pend stable since last barrier)
      const float sc  = (tier == 0) ? 32.0f : (tier == 1) ? 8.0f : 0.25f;
      const float rng = 64.0f / sc;   // 2 / 8 / 256
      // fill (only rows still pending; PREFILTER: only in-range elements)
#pragma unroll
      for (int reg = 0; reg < 4; ++reg) {
        int rloc = 4 * g + reg;
        if (kB_s[rloc] < 0) {
          float mx = mx_s[rloc];
          float thr = mx - rng;
#pragma unroll
          for (int tt = 0; tt < 16; ++tt) {
            float v = s[tt][reg];
            if (v >= thr) {
              int bb = (int)((mx - v) * sc);
              bb = bb > 63 ? 63 : bb;
              atomicAdd(&hist[rloc][bb], 1u);
            }
          }
        }
      }
      __syncthreads();
      // scan: 2 rows/wave, 32 lanes/row
      {
        bool rowpend = (kB_s[rw] < 0);
        unsigned cnt2 = rowpend ? (hist[rw][c32 * 2] + hist[rw][c32 * 2 + 1]) : 0u;
        unsigned pre = cnt2;
#pragma unroll
        for (int off = 1; off < 32; off <<= 1) {
          unsigned t = __shfl_up(pre, (unsigned)off, 32);
          if (c32 >= off) pre += t;
        }
        unsigned excl = pre - cnt2;
        bool flag = rowpend && (excl < 32u) && (pre >= 32u);
        unsigned long long bal = __ballot(flag);
        unsigned seg = (unsigned)((bal >> (h32 * 32)) & 0xFFFFFFFFull);
        bool resolved = false;
        if (flag) {
          int src = __ffs(seg) - 1;
          if (c32 == src) {
            unsigned cum = excl;
            int B = 63;
#pragma unroll
            for (int i = 0; i < 2; ++i) {
              unsigned hv = hist[rw][c32 * 2 + i];
              if (cum < 32u && cum + hv >= 32u) B = c32 * 2 + i;
              cum += hv;
            }
            if (B < 63 || tier == 2) {     // bucket 63 = clamp risk -> next tier
              kB_s[rw] = B;
              eHi_s[rw] = mx_s[rw] - (float)B / sc;
              eLo_s[rw] = mx_s[rw] - (float)(B + 1) / sc;
              atomicSub(&pend, 1u);
              resolved = true;
            }
          }
        }
        if (tier < 2) {
          unsigned long long bal2 = __ballot(resolved);
          bool rowResolved = (((bal2 >> (h32 * 32)) & 0xFFFFFFFFull) != 0ull);
          if (rowpend && !rowResolved) {   // re-zero for next tier
            hist[rw][c32] = 0u;
            hist[rw][c32 + 32] = 0u;
          }
        }
      }
      __syncthreads();
    }
  }
  // after tiers: b3/b4 on common path

  // ---- classify: v > eHi+D -> definite-in; [eLo-D, eHi+D] -> band ----
#pragma unroll
  for (int reg = 0; reg < 4; ++reg) {
    int rloc = 4 * g + reg;
    float eh = eHi_s[rloc] + DELTA;
    float el = eLo_s[rloc] - DELTA;
    unsigned cnt = 0;
#pragma unroll
    for (int tt = 0; tt < 16; ++tt) {
      float v = s[tt][reg];
      if (v > eh) {
        ++cnt;
        unsigned slot = atomicAdd(&scnt[rloc], 1u);
        if (slot < (unsigned)SLOTS) {
          sval[rloc][slot] = v;
          scol[rloc][slot] = (unsigned short)(w * 256 + tt * 16 + li);
        }
      } else if (v >= el) {
        unsigned slot = atomicAdd(&bcnt[rloc], 1u);
        if (slot < (unsigned)MAXB) {
          bidx[rloc][slot] = (unsigned short)(w * 256 + tt * 16 + li);
          bval[rloc][slot] = v;
        }
      }
    }
#pragma unroll
    for (int off = 1; off < 16; off <<= 1)
      cnt += (unsigned)__shfl_xor((int)cnt, off, 16);
    if (li == 0 && cnt) atomicAdd(&chi_s[rloc], cnt);
  }
  __syncthreads();   // b5

  // ---- zero-fill (REGULAR stores -> L2; drains fast at b6) ----
  float* base = attn + prow0 * 2048;
  {
    f32x4 z4 = {0.f, 0.f, 0.f, 0.f};
#pragma unroll
    for (int it = 0; it < 16; ++it)
      ((f32x4*)base)[tid + 512 * it] = z4;
  }

  // ---- f64 refinement of band: 2 rows/wave, 32 lanes/row ----
  {
    unsigned bn = bcnt[rw];
    bn = bn > (unsigned)MAXB ? (unsigned)MAXB : bn;
    const double* qrow =
        qd + ((size_t)(b * 2048 + rowtile * 16 + rw)) * 256 + hh * 32;
    for (unsigned ci = (unsigned)c32; ci < bn; ci += 32u) {
      int m = bidx[rw][ci];
      const double* krow = kd + ((size_t)(b * 2048 + m)) * 256 + hh * 32;
      double acc = 0.0;
#pragma unroll 8
      for (int d = 0; d < 32; ++d) acc = fma(qrow[d], krow[d], acc);
      bs64[rw][ci] = acc * INV64;
    }
    unsigned need2 = 32u - chi_s[rw];
    for (unsigned ci = (unsigned)c32; ci < bn; ci += 32u) {
      double x = bs64[rw][ci];
      unsigned r = 0;
      for (unsigned jj = 0; jj < bn; ++jj)
        r += (bs64[rw][jj] > x) ? 1u : 0u;
      if (r < need2) {   // kept after exact f64 ranking (ties: all kept)
        unsigned slot = atomicAdd(&scnt[rw], 1u);
        if (slot < (unsigned)SLOTS) {
          sval[rw][slot] = bval[rw][ci];
          scol[rw][slot] = bidx[rw][ci];
        }
      }
    }
  }
  __syncthreads();   // b6

  // ---- Z (exp once, written back): 2 rows/wave ----
  {
    unsigned n = scnt[rw];
    n = n > (unsigned)SLOTS ? (unsigned)SLOTS : n;
    float mx = mx_s[rw];
    float z = 0.0f;
    for (unsigned i = (unsigned)c32; i < n; i += 32u) {
      float e = __expf(sval[rw][i] - mx);
      sval[rw][i] = e;
      z += e;
    }
#pragma unroll
    for (int off = 1; off < 32; off <<= 1) z += __shfl_xor(z, (unsigned)off, 32);
    if (c32 == 0) zinv_s[rw] = 1.0f / z;
  }
  __syncthreads();   // b7: Z done, zero stores drained

  // ---- scatter nonzeros + coalesced sidecar store ----
  for (int e = tid; e < 16 * SLOTS; e += 512) {
    int rr = e / SLOTS, ii = e % SLOTS;
    unsigned n = scnt[rr];
    n = n > (unsigned)SLOTS ? (unsigned)SLOTS : n;
    float p = 0.0f;
    unsigned short c = 0;
    if ((unsigned)ii < n) {
      c = scol[rr][ii];
      p = sval[rr][ii] * zinv_s[rr];
      base[(size_t)rr * 2048 + c] = p;
    }
    pval[prow0 * SLOTS + e] = p;
    pidx[prow0 * SLOTS + e] = c;
  }
}

// ---------------------------------------------------------------------------
// Fused sparse-PV + wo-lowrank + es-lowrank (f32 math post-selection).
// Block = PVR n-rows of one batch, all 8 heads. Emits pre-split elh/ell.
// ---------------------------------------------------------------------------
__global__ __launch_bounds__(256) void pv_wo_es_kernel(
    const float* __restrict__ pval, const unsigned short* __restrict__ pidx,
    const float* __restrict__ v,
    const float* __restrict__ wo_u, const float* __restrict__ wo_v,
    const float* __restrict__ es_u, const float* __restrict__ es_v,
    unsigned short* __restrict__ elh, unsigned short* __restrict__ ell) {
  __shared__ float svals[PVR][8][SLOTS];
  __shared__ unsigned short sidx[PVR][8][SLOTS];
  __shared__ float outr[PVR][256];
  __shared__ float mid[PVR][64];
  __shared__ float h2r[PVR][256];

  int tid = threadIdx.x;
  int bb = blockIdx.x >> 9;
  int rg = blockIdx.x & 511;
  int n0 = rg * PVR;

  for (int e = tid; e < PVR * 8 * SLOTS; e += 256) {
    int rr = e / (8 * SLOTS);
    int rem = e % (8 * SLOTS);
    int hh = rem / SLOTS, ii = rem % SLOTS;
    size_t srow = ((size_t)(bb * 8 + hh) * 2048 + n0 + rr) * SLOTS + ii;
    svals[rr][hh][ii] = pval[srow];
    sidx[rr][hh][ii] = pidx[srow];
  }
  __syncthreads();

  {
    int d = tid, hh = d >> 5;
    const float* vb = v + (size_t)bb * 2048 * 256 + d;
    for (int r = 0; r < PVR; ++r) {
      float acc = 0.f;
#pragma unroll 4
      for (int i = 0; i < SLOTS; ++i) {
        float p = svals[r][hh][i];
        int m = sidx[r][hh][i];
        acc = fmaf(p, vb[(size_t)m * 256], acc);
      }
      outr[r][d] = acc;
    }
  }
  __syncthreads();

  {
    int j = tid & 63, rb = tid >> 6;
    for (int r = rb; r < PVR; r += 4) {
      float a0 = 0, a1 = 0, a2 = 0, a3 = 0;
#pragma unroll 8
      for (int k4 = 0; k4 < 64; ++k4) {
        int k = k4 * 4;
        a0 = fmaf(outr[r][k + 0], wo_u[(k + 0) * 64 + j], a0);
        a1 = fmaf(outr[r][k + 1], wo_u[(k + 1) * 64 + j], a1);
        a2 = fmaf(outr[r][k + 2], wo_u[(k + 2) * 64 + j], a2);
        a3 = fmaf(outr[r][k + 3], wo_u[(k + 3) * 64 + j], a3);
      }
      mid[r][j] = (a0 + a1) + (a2 + a3);
    }
  }
  __syncthreads();

  {
    int c = tid;
    for (int r = 0; r < PVR; ++r) {
      float a0 = 0, a1 = 0, a2 = 0, a3 = 0;
#pragma unroll 4
      for (int k4 = 0; k4 < 16; ++k4) {
        int k = k4 * 4;
        a0 = fmaf(mid[r][k + 0], wo_v[(k + 0) * 256 + c], a0);
        a1 = fmaf(mid[r][k + 1], wo_v[(k + 1) * 256 + c], a1);
        a2 = fmaf(mid[r][k + 2], wo_v[(k + 2) * 256 + c], a2);
        a3 = fmaf(mid[r][k + 3], wo_v[(k + 3) * 256 + c], a3);
      }
      h2r[r][c] = (a0 + a1) + (a2 + a3);
    }
  }
  __syncthreads();

  {
    int j = tid & 63, rb = tid >> 6;
    for (int r = rb; r < PVR; r += 4) {
      float a0 = 0, a1 = 0, a2 = 0, a3 = 0;
#pragma unroll 8
      for (int k4 = 0; k4 < 64; ++k4) {
        int k = k4 * 4;
        a0 = fmaf(h2r[r][k + 0], es_u[(k + 0) * 64 + j], a0);
        a1 = fmaf(h2r[r][k + 1], es_u[(k + 1) * 64 + j], a1);
        a2 = fmaf(h2r[r][k + 2], es_u[(k + 2) * 64 + j], a2);
        a3 = fmaf(h2r[r][k + 3], es_u[(k + 3) * 64 + j], a3);
      }
      mid[r][j] = (a0 + a1) + (a2 + a3);
    }
  }
  __syncthreads();

  {
    int c = tid;
    for (int r = 0; r < PVR; ++r) {
      float a0 = 0, a1 = 0, a2 = 0, a3 = 0;
#pragma unroll 4
      for (int k4 = 0; k4 < 16; ++k4) {
        int k = k4 * 4;
        a0 = fmaf(mid[r][k + 0], es_v[(k + 0) * 256 + c], a0);
        a1 = fmaf(mid[r][k + 1], es_v[(k + 1) * 256 + c], a1);
        a2 = fmaf(mid[r][k + 2], es_v[(k + 2) * 256 + c], a2);
        a3 = fmaf(mid[r][k + 3], es_v[(k + 3) * 256 + c], a3);
      }
      float o = (a0 + a1) + (a2 + a3);
      size_t addr = ((size_t)(bb * 2048 + n0 + r)) * 256 + c;
      unsigned short hi = bf16_hi(o);
      elh[addr] = hi;
      ell[addr] = bf16_hi(o - bf16_val(hi));
    }
  }
}

// ---------------------------------------------------------------------------
// adjacency = sigmoid(el @ el^T), zero diagonal, via MFMA bf16 hi/lo 3-term.
// ---------------------------------------------------------------------------
__global__ __launch_bounds__(256) void adj_mfma_kernel(
    const unsigned short* __restrict__ elh, const unsigned short* __restrict__ ell,
    float* __restrict__ adj) {
  int tid = threadIdx.x;
  int l = tid & 63, w = tid >> 6;
  int li = l & 15, g = l >> 4;
  int b = blockIdx.z, rt = blockIdx.y, ct = blockIdx.x;

  int arow = rt * 64 + w * 16 + li;
  size_t abase = ((size_t)(b * 2048 + arow)) * 256 + g * 8;
  size_t bbase = ((size_t)(b * 2048 + ct * 64 + li)) * 256 + g * 8;

  f32x4 acc0 = {0.f, 0.f, 0.f, 0.f};
  f32x4 acc1 = {0.f, 0.f, 0.f, 0.f};
  f32x4 acc2 = {0.f, 0.f, 0.f, 0.f};
  f32x4 acc3 = {0.f, 0.f, 0.f, 0.f};

#pragma unroll
  for (int kc = 0; kc < 8; ++kc) {
    bf16x8 a_hi = *(const bf16x8*)(elh + abase + kc * 32);
    bf16x8 a_lo = *(const bf16x8*)(ell + abase + kc * 32);
#pragma unroll
    for (int t = 0; t < 4; ++t) {
      bf16x8 b_hi = *(const bf16x8*)(elh + bbase + (size_t)t * 16 * 256 + kc * 32);
      bf16x8 b_lo = *(const bf16x8*)(ell + bbase + (size_t)t * 16 * 256 + kc * 32);
      f32x4* pa = (t == 0) ? &acc0 : (t == 1) ? &acc1 : (t == 2) ? &acc2 : &acc3;
      *pa = __builtin_amdgcn_mfma_f32_16x16x32_bf16(a_hi, b_hi, *pa, 0, 0, 0);
      *pa = __builtin_amdgcn_mfma_f32_16x16x32_bf16(a_hi, b_lo, *pa, 0, 0, 0);
      *pa = __builtin_amdgcn_mfma_f32_16x16x32_bf16(a_lo, b_hi, *pa, 0, 0, 0);
    }
  }

  int orow0 = rt * 64 + w * 16 + g * 4;
#pragma unroll
  for (int t = 0; t < 4; ++t) {
    f32x4 a = (t == 0) ? acc0 : (t == 1) ? acc1 : (t == 2) ? acc2 : acc3;
    int cg = ct * 64 + t * 16 + li;
#pragma unroll
    for (int i = 0; i < 4; ++i) {
      int rg = orow0 + i;
      float sg = 1.0f / (1.0f + __expf(-a[i]));
      if (rg == cg) sg = 0.0f;
      adj[((size_t)b * 2048 + rg) * 2048 + cg] = sg;
    }
  }
}

// ---------------------------------------------------------------------------
extern "C" void kernel_launch(void* const* d_in, const int* in_sizes, int n_in,
                              void* d_out, int out_size, void* d_ws,
                              size_t ws_size, hipStream_t stream) {
  const float* x    = (const float*)d_in[0];
  const float* ne_u = (const float*)d_in[1];
  const float* ne_v = (const float*)d_in[2];
  const float* wq_u = (const float*)d_in[3];
  const float* wq_v = (const float*)d_in[4];
  const float* wk_u = (const float*)d_in[5];
  const float* wk_v = (const float*)d_in[6];
  const float* wv_u = (const float*)d_in[7];
  const float* wv_v = (const float*)d_in[8];
  const float* wo_u = (const float*)d_in[9];
  const float* wo_v = (const float*)d_in[10];
  const float* es_u = (const float*)d_in[11];
  const float* es_v = (const float*)d_in[12];

  float* adj  = (float*)d_out;
  float* attn = adj + (size_t)ATTN_OFF;

  // Workspace map (38.2 MB peak, lifetime-overlapped):
  //   qd 0..8M, kd 8..16M (f64, live thru attn; elh/ell overlay kd after)
  //   qh 16..18, ql 18..20, kh 20..22, kl 22..24 (bf16 split)
  //   v 24..28M f32 ; pval 28..34.3M f32 ; pidx 35..38.2M u16
  char* ws = (char*)d_ws;
  double* qd = (double*)(ws);
  double* kd = (double*)(ws + ((size_t)8  << 20));
  unsigned short* qh = (unsigned short*)(ws + ((size_t)16 << 20));
  unsigned short* ql = (unsigned short*)(ws + ((size_t)18 << 20));
  unsigned short* kh = (unsigned short*)(ws + ((size_t)20 << 20));
  unsigned short* kl = (unsigned short*)(ws + ((size_t)22 << 20));
  float* v    = (float*)(ws + ((size_t)24 << 20));
  float* pval = (float*)(ws + ((size_t)28 << 20));
  unsigned short* pidx = (unsigned short*)(ws + ((size_t)35 << 20));
  unsigned short* elh = (unsigned short*)(ws + ((size_t)8  << 20)); // overlays kd
  unsigned short* ell = (unsigned short*)(ws + ((size_t)10 << 20)); // overlays kd

  fused_qkv_kernel<<<1024, 256, 0, stream>>>(
      x, ne_u, ne_v, wq_u, wq_v, wk_u, wk_v, wv_u, wv_v,
      qd, kd, qh, ql, kh, kl, v);

  attn_kernel<<<2048, 512, 0, stream>>>(qh, ql, kh, kl, qd, kd, attn, pval, pidx);
  pv_wo_es_kernel<<<1024, 256, 0, stream>>>(pval, pidx, v, wo_u, wo_v,
                                            es_u, es_v, elh, ell);

  adj_mfma_kernel<<<dim3(32, 32, 2), 256, 0, stream>>>(elh, ell, adj);
}

// Round 14
// 361.154 us; speedup vs baseline: 1.0828x; 1.0828x over previous
//
#include <hip/hip_runtime.h>
#include <hip/hip_bf16.h>
#include <cstdint>
#include <cstddef>

#define ATTN_OFF (2u*2048u*2048u)   // adjacency comes first in d_out
#define SLOTS 48                    // compact top-k slots per row
#define DELTA 1e-3f                 // band half-margin (>> bf16-split score err)
#define MAXB 32                     // max boundary elems per row
#define PVR 4                       // rows per pv_wo_es block

typedef __attribute__((ext_vector_type(8))) short bf16x8;
typedef __attribute__((ext_vector_type(4))) float f32x4;

__device__ __forceinline__ unsigned short bf16_hi(float f) {
  __hip_bfloat16 h = __float2bfloat16(f);
  return *(unsigned short*)&h;
}
__device__ __forceinline__ float bf16_val(unsigned short u) {
  __hip_bfloat16 h = *(__hip_bfloat16*)&u;
  return __bfloat162float(h);
}

// ---------------------------------------------------------------------------
// Fused node-embedding + Q/K/V low-rank chain, f64 math throughout. (R6 ok)
// ---------------------------------------------------------------------------
__global__ __launch_bounds__(256) void fused_qkv_kernel(
    const float* __restrict__ x, const float* __restrict__ ne_u,
    const float* __restrict__ ne_v, const float* __restrict__ wq_u,
    const float* __restrict__ wq_v, const float* __restrict__ wk_u,
    const float* __restrict__ wk_v, const float* __restrict__ wv_u,
    const float* __restrict__ wv_v, double* __restrict__ qd,
    double* __restrict__ kd, unsigned short* __restrict__ qh,
    unsigned short* __restrict__ ql, unsigned short* __restrict__ kh,
    unsigned short* __restrict__ kl, float* __restrict__ v) {
  __shared__ double xm[4][64];
  __shared__ double hrow[4][256];
  __shared__ double mid2[4][64];

  int tid = threadIdx.x;
  int rr = tid >> 6;
  int j  = tid & 63;
  int row = blockIdx.x * 4 + rr;
  int b = row >> 11, m = row & 2047;
  const double INV = 0.17677669529663688110021109052621;  // 1/sqrt(32)

  const float* xr = x + (size_t)row * 256;
  {
    double a0 = 0, a1 = 0, a2 = 0, a3 = 0;
#pragma unroll 8
    for (int k4 = 0; k4 < 64; ++k4) {
      int kk = k4 * 4;
      a0 = fma((double)xr[kk + 0], (double)ne_u[(kk + 0) * 64 + j], a0);
      a1 = fma((double)xr[kk + 1], (double)ne_u[(kk + 1) * 64 + j], a1);
      a2 = fma((double)xr[kk + 2], (double)ne_u[(kk + 2) * 64 + j], a2);
      a3 = fma((double)xr[kk + 3], (double)ne_u[(kk + 3) * 64 + j], a3);
    }
    xm[rr][j] = (a0 + a1) + (a2 + a3);
  }
  __syncthreads();

#pragma unroll
  for (int cc = 0; cc < 4; ++cc) {
    int col = j + 64 * cc;
    double o0 = 0, o1 = 0, o2 = 0, o3 = 0;
#pragma unroll 4
    for (int r4 = 0; r4 < 16; ++r4) {
      int r = r4 * 4;
      o0 = fma(xm[rr][r + 0], (double)ne_v[(r + 0) * 256 + col], o0);
      o1 = fma(xm[rr][r + 1], (double)ne_v[(r + 1) * 256 + col], o1);
      o2 = fma(xm[rr][r + 2], (double)ne_v[(r + 2) * 256 + col], o2);
      o3 = fma(xm[rr][r + 3], (double)ne_v[(r + 3) * 256 + col], o3);
    }
    hrow[rr][col] = (o0 + o1) + (o2 + o3);
  }
  __syncthreads();

  for (int p = 0; p < 3; ++p) {
    const float* pu = (p == 0) ? wq_u : (p == 1) ? wk_u : wv_u;
    const float* pw = (p == 0) ? wq_v : (p == 1) ? wk_v : wv_v;

    double a0 = 0, a1 = 0, a2 = 0, a3 = 0;
#pragma unroll 8
    for (int k4 = 0; k4 < 64; ++k4) {
      int kk = k4 * 4;
      a0 = fma(hrow[rr][kk + 0], (double)pu[(kk + 0) * 64 + j], a0);
      a1 = fma(hrow[rr][kk + 1], (double)pu[(kk + 1) * 64 + j], a1);
      a2 = fma(hrow[rr][kk + 2], (double)pu[(kk + 2) * 64 + j], a2);
      a3 = fma(hrow[rr][kk + 3], (double)pu[(kk + 3) * 64 + j], a3);
    }
    mid2[rr][j] = (a0 + a1) + (a2 + a3);
    __syncthreads();

#pragma unroll
    for (int cc = 0; cc < 4; ++cc) {
      int col = j + 64 * cc;
      double o0 = 0, o1 = 0, o2 = 0, o3 = 0;
#pragma unroll 4
      for (int r4 = 0; r4 < 16; ++r4) {
        int r = r4 * 4;
        o0 = fma(mid2[rr][r + 0], (double)pw[(r + 0) * 256 + col], o0);
        o1 = fma(mid2[rr][r + 1], (double)pw[(r + 1) * 256 + col], o1);
        o2 = fma(mid2[rr][r + 2], (double)pw[(r + 2) * 256 + col], o2);
        o3 = fma(mid2[rr][r + 3], (double)pw[(r + 3) * 256 + col], o3);
      }
      double o = (o0 + o1) + (o2 + o3);
      if (p == 2) {
        v[(size_t)row * 256 + col] = (float)o;
      } else {
        int hh = col >> 5, d = col & 31;
        size_t haddr = (((size_t)(b * 8 + hh)) * 2048 + m) * 32 + d;
        if (p == 0) {
          qd[(size_t)row * 256 + col] = o;
          float f = (float)(o * INV);
          unsigned short hi = bf16_hi(f);
          float lof = f - bf16_val(hi);
          qh[haddr] = hi;
          ql[haddr] = bf16_hi(lof);
        } else {
          kd[(size_t)row * 256 + col] = o;
          float f = (float)o;
          unsigned short hi = bf16_hi(f);
          float lof = f - bf16_val(hi);
          kh[haddr] = hi;
          kl[haddr] = bf16_hi(lof);
        }
      }
    }
    __syncthreads();
  }
}

// ---------------------------------------------------------------------------
// Fused scores (MFMA bf16 hi/lo 3-term) + exact top-32 via bucket-band
// selection (tiered histogram with range prefilter) + f64 band refinement +
// softmax + coalesced dense write (NT zero-fill: write-once stream, bypass
// L2 -- R12/R13 A/B showed L2-cached fill is 30us WORSE from L2 pollution).
// Row-max reduced per-thread after b1 (identical fmaxf chain on all threads
// -> bitwise-identical mx, consistent bucket edges). 6 barriers common path.
// ---------------------------------------------------------------------------
__global__ __launch_bounds__(512, 4) void attn_kernel(
    const unsigned short* __restrict__ qh, const unsigned short* __restrict__ ql,
    const unsigned short* __restrict__ kh, const unsigned short* __restrict__ kl,
    const double* __restrict__ qd, const double* __restrict__ kd,
    float* __restrict__ attn, float* __restrict__ pval,
    unsigned short* __restrict__ pidx) {
  __shared__ unsigned hist[16][64];
  __shared__ float sval[16][SLOTS];            // raw scores, then exp values
  __shared__ unsigned short scol[16][SLOTS];
  __shared__ float rowmax_s[16][8];
  __shared__ float eLo_s[16], eHi_s[16];
  __shared__ float zinv_s[16];
  __shared__ int   kB_s[16];
  __shared__ unsigned scnt[16];
  __shared__ unsigned chi_s[16];
  __shared__ unsigned bcnt[16];
  __shared__ unsigned pend;
  __shared__ unsigned short bidx[16][MAXB];
  __shared__ float bval[16][MAXB];
  __shared__ double bs64[16][MAXB];

  int tid = threadIdx.x;
  int bx  = blockIdx.x;
  int slab = bx >> 7;
  int rowtile = bx & 127;
  int b = slab >> 3, hh = slab & 7;
  int w = tid >> 6;
  int l = tid & 63;
  int g = l >> 4;
  int li = l & 15;
  int h32 = l >> 5;            // 0/1: which 32-lane half of the wave
  int c32 = l & 31;            // lane within half
  int rw = w * 2 + h32;        // row owned in wide phases
  const double INV64 = 0.17677669529663688110021109052621;

  // ---- MFMA scores: 16 tiles x 3 (hi/lo split) ----
  size_t qoff = (((size_t)slab * 2048 + rowtile * 16 + li) * 32) + g * 8;
  bf16x8 a_hi = *(const bf16x8*)(qh + qoff);
  bf16x8 a_lo = *(const bf16x8*)(ql + qoff);

  float s[16][4];
  size_t kbase = ((size_t)slab * 2048 + w * 256 + li) * 32 + g * 8;
#pragma unroll
  for (int tt = 0; tt < 16; ++tt) {
    bf16x8 b_hi = *(const bf16x8*)(kh + kbase + (size_t)tt * 512);
    bf16x8 b_lo = *(const bf16x8*)(kl + kbase + (size_t)tt * 512);
    f32x4 acc = {0.f, 0.f, 0.f, 0.f};
    acc = __builtin_amdgcn_mfma_f32_16x16x32_bf16(a_hi, b_hi, acc, 0, 0, 0);
    acc = __builtin_amdgcn_mfma_f32_16x16x32_bf16(a_hi, b_lo, acc, 0, 0, 0);
    acc = __builtin_amdgcn_mfma_f32_16x16x32_bf16(a_lo, b_hi, acc, 0, 0, 0);
#pragma unroll
    for (int reg = 0; reg < 4; ++reg) s[tt][reg] = acc[reg];
  }

  // ---- init + per-slice row max ----
  for (int i = tid; i < 16 * 64; i += 512) ((unsigned*)hist)[i] = 0u;
  if (tid < 16) {
    scnt[tid] = 0u; chi_s[tid] = 0u; bcnt[tid] = 0u;
    kB_s[tid] = -1;
  }
  if (tid == 0) pend = 16u;
  size_t prow0 = ((size_t)slab * 2048 + rowtile * 16);
  {
    float lmx[4];
#pragma unroll
    for (int reg = 0; reg < 4; ++reg) {
      float m = s[0][reg];
#pragma unroll
      for (int tt = 1; tt < 16; ++tt) m = fmaxf(m, s[tt][reg]);
      lmx[reg] = m;
    }
#pragma unroll
    for (int off = 1; off < 16; off <<= 1) {
#pragma unroll
      for (int reg = 0; reg < 4; ++reg)
        lmx[reg] = fmaxf(lmx[reg], __shfl_xor(lmx[reg], (unsigned)off, 16));
    }
    if (li == 0) {
#pragma unroll
      for (int reg = 0; reg < 4; ++reg) rowmax_s[4 * g + reg][w] = lmx[reg];
    }
  }
  __syncthreads();   // b1

  // ---- per-thread row max (identical linear chain -> identical results) ----
  float mxr[4];
#pragma unroll
  for (int reg = 0; reg < 4; ++reg) {
    float m = rowmax_s[4 * g + reg][0];
#pragma unroll
    for (int i = 1; i < 8; ++i) m = fmaxf(m, rowmax_s[4 * g + reg][i]);
    mxr[reg] = m;
  }
  float mxw;
  {
    float m = rowmax_s[rw][0];
#pragma unroll
    for (int i = 1; i < 8; ++i) m = fmaxf(m, rowmax_s[rw][i]);
    mxw = m;
  }

  // ---- tiered histogram: locate kth bucket (tier 0 almost always) ----
#pragma unroll
  for (int tier = 0; tier < 3; ++tier) {
    if (pend != 0u) {      // block-uniform (pend stable since last barrier)
      const float sc  = (tier == 0) ? 32.0f : (tier == 1) ? 8.0f : 0.25f;
      const float rng = 64.0f / sc;   // 2 / 8 / 256
      // fill (only rows still pending; PREFILTER: only in-range elements)
#pragma unroll
      for (int reg = 0; reg < 4; ++reg) {
        int rloc = 4 * g + reg;
        if (kB_s[rloc] < 0) {
          float mx = mxr[reg];
          float thr = mx - rng;
#pragma unroll
          for (int tt = 0; tt < 16; ++tt) {
            float v = s[tt][reg];
            if (v >= thr) {
              int bb = (int)((mx - v) * sc);
              bb = bb > 63 ? 63 : bb;
              atomicAdd(&hist[rloc][bb], 1u);
            }
          }
        }
      }
      __syncthreads();
      // scan: 2 rows/wave, 32 lanes/row
      {
        bool rowpend = (kB_s[rw] < 0);
        unsigned cnt2 = rowpend ? (hist[rw][c32 * 2] + hist[rw][c32 * 2 + 1]) : 0u;
        unsigned pre = cnt2;
#pragma unroll
        for (int off = 1; off < 32; off <<= 1) {
          unsigned t = __shfl_up(pre, (unsigned)off, 32);
          if (c32 >= off) pre += t;
        }
        unsigned excl = pre - cnt2;
        bool flag = rowpend && (excl < 32u) && (pre >= 32u);
        unsigned long long bal = __ballot(flag);
        unsigned seg = (unsigned)((bal >> (h32 * 32)) & 0xFFFFFFFFull);
        bool resolved = false;
        if (flag) {
          int src = __ffs(seg) - 1;
          if (c32 == src) {
            unsigned cum = excl;
            int B = 63;
#pragma unroll
            for (int i = 0; i < 2; ++i) {
              unsigned hv = hist[rw][c32 * 2 + i];
              if (cum < 32u && cum + hv >= 32u) B = c32 * 2 + i;
              cum += hv;
            }
            if (B < 63 || tier == 2) {     // bucket 63 = clamp risk -> next tier
              kB_s[rw] = B;
              eHi_s[rw] = mxw - (float)B / sc;
              eLo_s[rw] = mxw - (float)(B + 1) / sc;
              atomicSub(&pend, 1u);
              resolved = true;
            }
          }
        }
        if (tier < 2) {
          unsigned long long bal2 = __ballot(resolved);
          bool rowResolved = (((bal2 >> (h32 * 32)) & 0xFFFFFFFFull) != 0ull);
          if (rowpend && !rowResolved) {   // re-zero for next tier
            hist[rw][c32] = 0u;
            hist[rw][c32 + 32] = 0u;
          }
        }
      }
      __syncthreads();
    }
  }
  // after tiers: b2/b3 on common path

  // ---- classify: v > eHi+D -> definite-in; [eLo-D, eHi+D] -> band ----
#pragma unroll
  for (int reg = 0; reg < 4; ++reg) {
    int rloc = 4 * g + reg;
    float eh = eHi_s[rloc] + DELTA;
    float el = eLo_s[rloc] - DELTA;
    unsigned cnt = 0;
#pragma unroll
    for (int tt = 0; tt < 16; ++tt) {
      float v = s[tt][reg];
      if (v > eh) {
        ++cnt;
        unsigned slot = atomicAdd(&scnt[rloc], 1u);
        if (slot < (unsigned)SLOTS) {
          sval[rloc][slot] = v;
          scol[rloc][slot] = (unsigned short)(w * 256 + tt * 16 + li);
        }
      } else if (v >= el) {
        unsigned slot = atomicAdd(&bcnt[rloc], 1u);
        if (slot < (unsigned)MAXB) {
          bidx[rloc][slot] = (unsigned short)(w * 256 + tt * 16 + li);
          bval[rloc][slot] = v;
        }
      }
    }
#pragma unroll
    for (int off = 1; off < 16; off <<= 1)
      cnt += (unsigned)__shfl_xor((int)cnt, off, 16);
    if (li == 0 && cnt) atomicAdd(&chi_s[rloc], cnt);
  }
  __syncthreads();   // b4

  // ---- NT zero-fill issued early (drains under refine + Z) ----
  float* base = attn + prow0 * 2048;
  {
    f32x4 z4 = {0.f, 0.f, 0.f, 0.f};
#pragma unroll
    for (int it = 0; it < 16; ++it)
      __builtin_nontemporal_store(z4, ((f32x4*)base) + tid + 512 * it);
  }

  // ---- f64 refinement of band: 2 rows/wave, 32 lanes/row ----
  {
    unsigned bn = bcnt[rw];
    bn = bn > (unsigned)MAXB ? (unsigned)MAXB : bn;
    const double* qrow =
        qd + ((size_t)(b * 2048 + rowtile * 16 + rw)) * 256 + hh * 32;
    for (unsigned ci = (unsigned)c32; ci < bn; ci += 32u) {
      int m = bidx[rw][ci];
      const double* krow = kd + ((size_t)(b * 2048 + m)) * 256 + hh * 32;
      double acc = 0.0;
#pragma unroll 8
      for (int d = 0; d < 32; ++d) acc = fma(qrow[d], krow[d], acc);
      bs64[rw][ci] = acc * INV64;
    }
    unsigned need2 = 32u - chi_s[rw];
    for (unsigned ci = (unsigned)c32; ci < bn; ci += 32u) {
      double x = bs64[rw][ci];
      unsigned r = 0;
      for (unsigned jj = 0; jj < bn; ++jj)
        r += (bs64[rw][jj] > x) ? 1u : 0u;
      if (r < need2) {   // kept after exact f64 ranking (ties: all kept)
        unsigned slot = atomicAdd(&scnt[rw], 1u);
        if (slot < (unsigned)SLOTS) {
          sval[rw][slot] = bval[rw][ci];
          scol[rw][slot] = bidx[rw][ci];
        }
      }
    }
  }
  __syncthreads();   // b5

  // ---- Z (exp once, written back): 2 rows/wave ----
  {
    unsigned n = scnt[rw];
    n = n > (unsigned)SLOTS ? (unsigned)SLOTS : n;
    float z = 0.0f;
    for (unsigned i = (unsigned)c32; i < n; i += 32u) {
      float e = __expf(sval[rw][i] - mxw);
      sval[rw][i] = e;
      z += e;
    }
#pragma unroll
    for (int off = 1; off < 32; off <<= 1) z += __shfl_xor(z, (unsigned)off, 32);
    if (c32 == 0) zinv_s[rw] = 1.0f / z;
  }
  __syncthreads();   // b6: Z done, zero stores drained

  // ---- scatter nonzeros + coalesced sidecar store ----
  for (int e = tid; e < 16 * SLOTS; e += 512) {
    int rr = e / SLOTS, ii = e % SLOTS;
    unsigned n = scnt[rr];
    n = n > (unsigned)SLOTS ? (unsigned)SLOTS : n;
    float p = 0.0f;
    unsigned short c = 0;
    if ((unsigned)ii < n) {
      c = scol[rr][ii];
      p = sval[rr][ii] * zinv_s[rr];
      base[(size_t)rr * 2048 + c] = p;
    }
    pval[prow0 * SLOTS + e] = p;
    pidx[prow0 * SLOTS + e] = c;
  }
}

// ---------------------------------------------------------------------------
// Fused sparse-PV + wo-lowrank + es-lowrank (f32 math post-selection).
// Block = PVR n-rows of one batch, all 8 heads. Emits pre-split elh/ell.
// ---------------------------------------------------------------------------
__global__ __launch_bounds__(256) void pv_wo_es_kernel(
    const float* __restrict__ pval, const unsigned short* __restrict__ pidx,
    const float* __restrict__ v,
    const float* __restrict__ wo_u, const float* __restrict__ wo_v,
    const float* __restrict__ es_u, const float* __restrict__ es_v,
    unsigned short* __restrict__ elh, unsigned short* __restrict__ ell) {
  __shared__ float svals[PVR][8][SLOTS];
  __shared__ unsigned short sidx[PVR][8][SLOTS];
  __shared__ float outr[PVR][256];
  __shared__ float mid[PVR][64];
  __shared__ float h2r[PVR][256];

  int tid = threadIdx.x;
  int bb = blockIdx.x >> 9;
  int rg = blockIdx.x & 511;
  int n0 = rg * PVR;

  for (int e = tid; e < PVR * 8 * SLOTS; e += 256) {
    int rr = e / (8 * SLOTS);
    int rem = e % (8 * SLOTS);
    int hh = rem / SLOTS, ii = rem % SLOTS;
    size_t srow = ((size_t)(bb * 8 + hh) * 2048 + n0 + rr) * SLOTS + ii;
    svals[rr][hh][ii] = pval[srow];
    sidx[rr][hh][ii] = pidx[srow];
  }
  __syncthreads();

  {
    int d = tid, hh = d >> 5;
    const float* vb = v + (size_t)bb * 2048 * 256 + d;
    for (int r = 0; r < PVR; ++r) {
      float acc = 0.f;
#pragma unroll 4
      for (int i = 0; i < SLOTS; ++i) {
        float p = svals[r][hh][i];
        int m = sidx[r][hh][i];
        acc = fmaf(p, vb[(size_t)m * 256], acc);
      }
      outr[r][d] = acc;
    }
  }
  __syncthreads();

  {
    int j = tid & 63, rb = tid >> 6;
    for (int r = rb; r < PVR; r += 4) {
      float a0 = 0, a1 = 0, a2 = 0, a3 = 0;
#pragma unroll 8
      for (int k4 = 0; k4 < 64; ++k4) {
        int k = k4 * 4;
        a0 = fmaf(outr[r][k + 0], wo_u[(k + 0) * 64 + j], a0);
        a1 = fmaf(outr[r][k + 1], wo_u[(k + 1) * 64 + j], a1);
        a2 = fmaf(outr[r][k + 2], wo_u[(k + 2) * 64 + j], a2);
        a3 = fmaf(outr[r][k + 3], wo_u[(k + 3) * 64 + j], a3);
      }
      mid[r][j] = (a0 + a1) + (a2 + a3);
    }
  }
  __syncthreads();

  {
    int c = tid;
    for (int r = 0; r < PVR; ++r) {
      float a0 = 0, a1 = 0, a2 = 0, a3 = 0;
#pragma unroll 4
      for (int k4 = 0; k4 < 16; ++k4) {
        int k = k4 * 4;
        a0 = fmaf(mid[r][k + 0], wo_v[(k + 0) * 256 + c], a0);
        a1 = fmaf(mid[r][k + 1], wo_v[(k + 1) * 256 + c], a1);
        a2 = fmaf(mid[r][k + 2], wo_v[(k + 2) * 256 + c], a2);
        a3 = fmaf(mid[r][k + 3], wo_v[(k + 3) * 256 + c], a3);
      }
      h2r[r][c] = (a0 + a1) + (a2 + a3);
    }
  }
  __syncthreads();

  {
    int j = tid & 63, rb = tid >> 6;
    for (int r = rb; r < PVR; r += 4) {
      float a0 = 0, a1 = 0, a2 = 0, a3 = 0;
#pragma unroll 8
      for (int k4 = 0; k4 < 64; ++k4) {
        int k = k4 * 4;
        a0 = fmaf(h2r[r][k + 0], es_u[(k + 0) * 64 + j], a0);
        a1 = fmaf(h2r[r][k + 1], es_u[(k + 1) * 64 + j], a1);
        a2 = fmaf(h2r[r][k + 2], es_u[(k + 2) * 64 + j], a2);
        a3 = fmaf(h2r[r][k + 3], es_u[(k + 3) * 64 + j], a3);
      }
      mid[r][j] = (a0 + a1) + (a2 + a3);
    }
  }
  __syncthreads();

  {
    int c = tid;
    for (int r = 0; r < PVR; ++r) {
      float a0 = 0, a1 = 0, a2 = 0, a3 = 0;
#pragma unroll 4
      for (int k4 = 0; k4 < 16; ++k4) {
        int k = k4 * 4;
        a0 = fmaf(mid[r][k + 0], es_v[(k + 0) * 256 + c], a0);
        a1 = fmaf(mid[r][k + 1], es_v[(k + 1) * 256 + c], a1);
        a2 = fmaf(mid[r][k + 2], es_v[(k + 2) * 256 + c], a2);
        a3 = fmaf(mid[r][k + 3], es_v[(k + 3) * 256 + c], a3);
      }
      float o = (a0 + a1) + (a2 + a3);
      size_t addr = ((size_t)(bb * 2048 + n0 + r)) * 256 + c;
      unsigned short hi = bf16_hi(o);
      elh[addr] = hi;
      ell[addr] = bf16_hi(o - bf16_val(hi));
    }
  }
}

// ---------------------------------------------------------------------------
// adjacency = sigmoid(el @ el^T), zero diagonal, via MFMA bf16 hi/lo 3-term.
// ---------------------------------------------------------------------------
__global__ __launch_bounds__(256) void adj_mfma_kernel(
    const unsigned short* __restrict__ elh, const unsigned short* __restrict__ ell,
    float* __restrict__ adj) {
  int tid = threadIdx.x;
  int l = tid & 63, w = tid >> 6;
  int li = l & 15, g = l >> 4;
  int b = blockIdx.z, rt = blockIdx.y, ct = blockIdx.x;

  int arow = rt * 64 + w * 16 + li;
  size_t abase = ((size_t)(b * 2048 + arow)) * 256 + g * 8;
  size_t bbase = ((size_t)(b * 2048 + ct * 64 + li)) * 256 + g * 8;

  f32x4 acc0 = {0.f, 0.f, 0.f, 0.f};
  f32x4 acc1 = {0.f, 0.f, 0.f, 0.f};
  f32x4 acc2 = {0.f, 0.f, 0.f, 0.f};
  f32x4 acc3 = {0.f, 0.f, 0.f, 0.f};

#pragma unroll
  for (int kc = 0; kc < 8; ++kc) {
    bf16x8 a_hi = *(const bf16x8*)(elh + abase + kc * 32);
    bf16x8 a_lo = *(const bf16x8*)(ell + abase + kc * 32);
#pragma unroll
    for (int t = 0; t < 4; ++t) {
      bf16x8 b_hi = *(const bf16x8*)(elh + bbase + (size_t)t * 16 * 256 + kc * 32);
      bf16x8 b_lo = *(const bf16x8*)(ell + bbase + (size_t)t * 16 * 256 + kc * 32);
      f32x4* pa = (t == 0) ? &acc0 : (t == 1) ? &acc1 : (t == 2) ? &acc2 : &acc3;
      *pa = __builtin_amdgcn_mfma_f32_16x16x32_bf16(a_hi, b_hi, *pa, 0, 0, 0);
      *pa = __builtin_amdgcn_mfma_f32_16x16x32_bf16(a_hi, b_lo, *pa, 0, 0, 0);
      *pa = __builtin_amdgcn_mfma_f32_16x16x32_bf16(a_lo, b_hi, *pa, 0, 0, 0);
    }
  }

  int orow0 = rt * 64 + w * 16 + g * 4;
#pragma unroll
  for (int t = 0; t < 4; ++t) {
    f32x4 a = (t == 0) ? acc0 : (t == 1) ? acc1 : (t == 2) ? acc2 : acc3;
    int cg = ct * 64 + t * 16 + li;
#pragma unroll
    for (int i = 0; i < 4; ++i) {
      int rg = orow0 + i;
      float sg = 1.0f / (1.0f + __expf(-a[i]));
      if (rg == cg) sg = 0.0f;
      adj[((size_t)b * 2048 + rg) * 2048 + cg] = sg;
    }
  }
}

// ---------------------------------------------------------------------------
extern "C" void kernel_launch(void* const* d_in, const int* in_sizes, int n_in,
                              void* d_out, int out_size, void* d_ws,
                              size_t ws_size, hipStream_t stream) {
  const float* x    = (const float*)d_in[0];
  const float* ne_u = (const float*)d_in[1];
  const float* ne_v = (const float*)d_in[2];
  const float* wq_u = (const float*)d_in[3];
  const float* wq_v = (const float*)d_in[4];
  const float* wk_u = (const float*)d_in[5];
  const float* wk_v = (const float*)d_in[6];
  const float* wv_u = (const float*)d_in[7];
  const float* wv_v = (const float*)d_in[8];
  const float* wo_u = (const float*)d_in[9];
  const float* wo_v = (const float*)d_in[10];
  const float* es_u = (const float*)d_in[11];
  const float* es_v = (const float*)d_in[12];

  float* adj  = (float*)d_out;
  float* attn = adj + (size_t)ATTN_OFF;

  // Workspace map (38.2 MB peak, lifetime-overlapped):
  //   qd 0..8M, kd 8..16M (f64, live thru attn; elh/ell overlay kd after)
  //   qh 16..18, ql 18..20, kh 20..22, kl 22..24 (bf16 split)
  //   v 24..28M f32 ; pval 28..34.3M f32 ; pidx 35..38.2M u16
  char* ws = (char*)d_ws;
  double* qd = (double*)(ws);
  double* kd = (double*)(ws + ((size_t)8  << 20));
  unsigned short* qh = (unsigned short*)(ws + ((size_t)16 << 20));
  unsigned short* ql = (unsigned short*)(ws + ((size_t)18 << 20));
  unsigned short* kh = (unsigned short*)(ws + ((size_t)20 << 20));
  unsigned short* kl = (unsigned short*)(ws + ((size_t)22 << 20));
  float* v    = (float*)(ws + ((size_t)24 << 20));
  float* pval = (float*)(ws + ((size_t)28 << 20));
  unsigned short* pidx = (unsigned short*)(ws + ((size_t)35 << 20));
  unsigned short* elh = (unsigned short*)(ws + ((size_t)8  << 20)); // overlays kd
  unsigned short* ell = (unsigned short*)(ws + ((size_t)10 << 20)); // overlays kd

  fused_qkv_kernel<<<1024, 256, 0, stream>>>(
      x, ne_u, ne_v, wq_u, wq_v, wk_u, wk_v, wv_u, wv_v,
      qd, kd, qh, ql, kh, kl, v);

  attn_kernel<<<2048, 512, 0, stream>>>(qh, ql, kh, kl, qd, kd, attn, pval, pidx);
  pv_wo_es_kernel<<<1024, 256, 0, stream>>>(pval, pidx, v, wo_u, wo_v,
                                            es_u, es_v, elh, ell);

  adj_mfma_kernel<<<dim3(32, 32, 2), 256, 0, stream>>>(elh, ell, adj);
}